// Round 11
// baseline (222.316 us; speedup 1.0000x reference)
//
#include <hip/hip_runtime.h>
#include <hip/hip_bf16.h>

#define SS 4
#define CC 128
#define KROW 288      // W k-stride per n-row (9 kt-spans x 32)
#define WELEM 18432   // 64 n-rows * 288 k  per (s,c)
#define NK3 23
#define NK2 5
#define NK1 2
#define DLP 72        // Dl row stride (ushorts); 144 B = 16B-aligned rows

typedef unsigned int uint;
typedef unsigned short ushort;
typedef __attribute__((ext_vector_type(8))) short bf16x8;
typedef __attribute__((ext_vector_type(4))) float f32x4;

__device__ __forceinline__ float bflo(uint u){ return __uint_as_float(u << 16); }
__device__ __forceinline__ float bfhi(uint u){ return __uint_as_float(u & 0xffff0000u); }
__device__ __forceinline__ ushort f2bf(float f) {
  uint u = __float_as_uint(f);
  return (ushort)((u + 0x7fffu + ((u >> 16) & 1u)) >> 16);
}
__device__ __forceinline__ uint pk2(float a, float b) {
  __hip_bfloat162 h = __float22bfloat162_rn(make_float2(a, b));  // v_cvt_pk_bf16_f32
  return *(uint*)&h;
}

// ============ pre_kernel: fold3 (blocks 0..511) + fold21 (512..1023) + sort (1024) ============
// W layout: [s][c][n=o*16+i][k 0..287] — k-contiguous so corr's per-lane B-frag
// (8 consecutive k) is one aligned b128 global load.
__global__ __launch_bounds__(256) void pre_kernel(
    const float* __restrict__ u3_0, const float* __restrict__ u3_1,
    const float* __restrict__ w3,
    const float* __restrict__ u2_0, const float* __restrict__ u2_1,
    const float* __restrict__ u1_0, const float* __restrict__ u1_1,
    const float* __restrict__ w2,  const float* __restrict__ w1,
    const int* __restrict__ sp, ushort* __restrict__ W,
    int* __restrict__ sorted, int* __restrict__ seg) {
  __shared__ float smem[5888 + NK3 * 64];
  int bx = blockIdx.x;
  int tid = threadIdx.x;

  if (bx < 512) {
    // ---- fold3: W main k=0..255, coalesced 512 B-run stores ----
    float* u3s = smem;            // 5888 floats
    float* w3s = smem + 5888;     // 23*64 floats
    int ch = bx & 1, i = (bx >> 1) & 15, o = (bx >> 5) & 3, s = bx >> 7;
    int g = (o > 0) ? 1 : 0, og = g ? (o - 1) : 0;
    const float* u3 = g ? u3_1 : u3_0;

    const float4* u3p = (const float4*)(u3 + (size_t)(og * 16 + i) * 5888);
    for (int d = tid; d < 1472; d += 256) {
      float4 v = u3p[d];
      u3s[4 * d] = v.x; u3s[4 * d + 1] = v.y; u3s[4 * d + 2] = v.z; u3s[4 * d + 3] = v.w;
    }
    for (int t = tid; t < NK3 * 64; t += 256) {
      int k = t >> 6, cp = t & 63;
      w3s[t] = w3[((size_t)(g * SS + s) * NK3 + k) * CC + ch * 64 + cp];
    }
    __syncthreads();

    float acc[64];
    #pragma unroll
    for (int q = 0; q < 64; q++) acc[q] = 0.f;
    int jl = tid;
    for (int k = 0; k < NK3; k++) {
      float u3v = u3s[jl * NK3 + k];
      const float4* wp = (const float4*)&w3s[k * 64];
      #pragma unroll
      for (int cq = 0; cq < 16; cq++) {
        float4 wv = wp[cq];
        acc[cq * 4 + 0] = fmaf(u3v, wv.x, acc[cq * 4 + 0]);
        acc[cq * 4 + 1] = fmaf(u3v, wv.y, acc[cq * 4 + 1]);
        acc[cq * 4 + 2] = fmaf(u3v, wv.z, acc[cq * 4 + 2]);
        acc[cq * 4 + 3] = fmaf(u3v, wv.w, acc[cq * 4 + 3]);
      }
    }
    int n = o * 16 + i;
    #pragma unroll
    for (int cp = 0; cp < 64; cp++) {
      W[(size_t)(s * CC + ch * 64 + cp) * WELEM + n * KROW + jl] = f2bf(acc[cp]);
    }
  } else if (bx < 1024) {
    // ---- fold21: W tail k=256..287 (one uint4 per thread) ----
    int b2 = bx - 512;
    int s = b2 >> 7, c = b2 & 127;
    int n = tid >> 2, lq = tid & 3;
    int o = n >> 4, i = n & 15;
    int g = (o > 0) ? 1 : 0, og = g ? (o - 1) : 0;
    const float* u2 = g ? u2_1 : u2_0;
    const float* u1 = g ? u1_1 : u1_0;

    float vals[8];
    #pragma unroll
    for (int t = 0; t < 8; t++) {
      int k = 256 + lq * 8 + t;
      float v = 0.f;
      if (k < 272) {
        int j = k - 256;
        #pragma unroll
        for (int k2 = 0; k2 < NK2; k2++)
          v = fmaf(u2[((size_t)(og * 16 + i) * 16 + j) * NK2 + k2],
                   w2[((size_t)(g * SS + s) * NK2 + k2) * CC + c], v);
      } else if (k == 272) {
        #pragma unroll
        for (int k2 = 0; k2 < NK1; k2++)
          v = fmaf(u1[(size_t)(og * 16 + i) * NK1 + k2],
                   w1[((size_t)(g * SS + s) * NK1 + k2) * CC + c], v);
      }
      vals[t] = v;
    }
    uint4 pk;
    pk.x = pk2(vals[0], vals[1]); pk.y = pk2(vals[2], vals[3]);
    pk.z = pk2(vals[4], vals[5]); pk.w = pk2(vals[6], vals[7]);
    *(uint4*)(W + (size_t)(s * CC + c) * WELEM + n * KROW + 256 + lq * 8) = pk;
  } else {
    // ---- sort nodes by species ----
    __shared__ int cnt[SS];
    __shared__ int basep[SS + 1];
    if (tid < SS) cnt[tid] = 0;
    __syncthreads();
    int mysp[4], mypos[4];
    #pragma unroll
    for (int q = 0; q < 4; q++) {
      int node = q * 256 + tid;
      int s = sp[node];
      mysp[q] = s;
      mypos[q] = atomicAdd(&cnt[s], 1);
    }
    __syncthreads();
    if (tid == 0) {
      basep[0] = 0;
      for (int q = 0; q < SS; q++) basep[q + 1] = basep[q] + cnt[q];
      for (int q = 0; q <= SS; q++) seg[q] = basep[q];
    }
    __syncthreads();
    #pragma unroll
    for (int q = 0; q < 4; q++)
      sorted[basep[mysp[q]] + mypos[q]] = q * 256 + tid;
  }
}

// ============ corr_kernel: MFMA symmetric contraction, B direct from L2 ============
// grid 1024 = h(2) x s(4) x c(128); 4 waves; wave w owns rows [w*16,w*16+16) of
// TWO slabs per iteration; block h handles pairs h, h+2, ...
// NO W LDS staging / NO barriers: each lane's B-fragment is one independent
// b128 global load (W is [n][k], k-contiguous; 4 lq-lanes share a 64 B line).
// The R3-R10 LDS-staged variants were all ~44-46 us latency-bound at 8 waves/CU;
// this trades the DS pipe for deep-MLP L2 reads (~147 MB @ ~35 TB/s).
__global__ __launch_bounds__(256, 3) void corr_kernel(
    const float* __restrict__ xg, const ushort* __restrict__ Wg,
    const int* __restrict__ sorted, const int* __restrict__ seg,
    float* __restrict__ y) {
  __shared__ __align__(16) float xl[2][4][16][20];   // 10 KB, [slot][w][ln][...]
  __shared__ __align__(16) ushort Dl[4 * 16 * DLP];  // 9 KB, per-wave region
  int bx = blockIdx.x;
  int h = bx >> 9, s = (bx >> 7) & 3, c = bx & 127;
  int tid = threadIdx.x;
  int w = tid >> 6, lane = tid & 63;
  int lq = lane >> 4, ln = lane & 15;

  const ushort* wgu = Wg + (size_t)(s * CC + c) * WELEM + ln * KROW + lq * 8;

  int s0 = seg[s], s1 = seg[s + 1];
  int nslab = (s1 - s0 + 63) >> 6;
  int npair = (nslab + 1) >> 1;

  // pre-stage x for pair h (slabs 2h, 2h+1)
  int sv0 = 0, sv1 = 0;
  if (h < npair) {
    int r0 = s0 + (2 * h) * 64 + w * 16 + ln;
    sv0 = sorted[min(r0, s1 - 1)];
    float4 v0 = *((const float4*)(xg + ((size_t)sv0 * CC + c) * 16) + lq);
    *(float4*)(&xl[0][w][ln][lq * 4]) = v0;
    int r1 = min(r0 + 64, s1 - 1);
    sv1 = sorted[r1];
    float4 v1 = *((const float4*)(xg + ((size_t)sv1 * CC + c) * 16) + lq);
    *(float4*)(&xl[1][w][ln][lq * 4]) = v1;
  }

  for (int t = h; t < npair; t += 2) {
    // own rows of both slabs from wave-private LDS (same-wave ordering, no barrier)
    float xvA[16], xvB[16];
    #pragma unroll
    for (int q = 0; q < 4; q++) {
      float4 va = *(const float4*)(&xl[0][w][ln][q * 4]);
      xvA[q * 4] = va.x; xvA[q * 4 + 1] = va.y; xvA[q * 4 + 2] = va.z; xvA[q * 4 + 3] = va.w;
      float4 vb = *(const float4*)(&xl[1][w][ln][q * 4]);
      xvB[q * 4] = vb.x; xvB[q * 4 + 1] = vb.y; xvB[q * 4 + 2] = vb.z; xvB[q * 4 + 3] = vb.w;
    }
    int svA = sv0, svB = sv1;
    int rowA = s0 + (2 * t) * 64 + w * 16 + ln;
    int rowB = rowA + 64;
    // prefetch next pair (overlaps MFMA); LDS writes deferred past epilogue
    float4 xc0 = make_float4(0.f, 0.f, 0.f, 0.f);
    float4 xc1 = make_float4(0.f, 0.f, 0.f, 0.f);
    bool pf = (t + 2 < npair);
    if (pf) {
      int r0 = s0 + (2 * t + 4) * 64 + w * 16 + ln;
      sv0 = sorted[min(r0, s1 - 1)];
      xc0 = *((const float4*)(xg + ((size_t)sv0 * CC + c) * 16) + lq);
      int r1 = min(r0 + 64, s1 - 1);
      sv1 = sorted[r1];
      xc1 = *((const float4*)(xg + ((size_t)sv1 * CC + c) * 16) + lq);
    }

    float xs8A[8], xs8B[8];
    #pragma unroll
    for (int q = 0; q < 8; q++) {
      xs8A[q] = (lq & 1) ? xvA[8 + q] : xvA[q];
      xs8B[q] = (lq & 1) ? xvB[8 + q] : xvB[q];
    }

    f32x4 accA[4], accB[4];
    #pragma unroll
    for (int nt = 0; nt < 4; nt++) {
      accA[nt] = (f32x4){0.f, 0.f, 0.f, 0.f};
      accB[nt] = (f32x4){0.f, 0.f, 0.f, 0.f};
    }

    #pragma unroll
    for (int kt = 0; kt < 9; kt++) {
      uint4 avA, avB;
      if (kt < 8) {
        float xjA = (lq & 2) ? xvA[kt * 2 + 1] : xvA[kt * 2];
        avA.x = pk2(xjA * xs8A[0], xjA * xs8A[1]);
        avA.y = pk2(xjA * xs8A[2], xjA * xs8A[3]);
        avA.z = pk2(xjA * xs8A[4], xjA * xs8A[5]);
        avA.w = pk2(xjA * xs8A[6], xjA * xs8A[7]);
        float xjB = (lq & 2) ? xvB[kt * 2 + 1] : xvB[kt * 2];
        avB.x = pk2(xjB * xs8B[0], xjB * xs8B[1]);
        avB.y = pk2(xjB * xs8B[2], xjB * xs8B[3]);
        avB.z = pk2(xjB * xs8B[4], xjB * xs8B[5]);
        avB.w = pk2(xjB * xs8B[6], xjB * xs8B[7]);
      } else {
        avA.x = pk2(xs8A[0], xs8A[1]); avA.y = pk2(xs8A[2], xs8A[3]);
        avA.z = pk2(xs8A[4], xs8A[5]); avA.w = pk2(xs8A[6], xs8A[7]);
        avB.x = pk2(xs8B[0], xs8B[1]); avB.y = pk2(xs8B[2], xs8B[3]);
        avB.z = pk2(xs8B[4], xs8B[5]); avB.w = pk2(xs8B[6], xs8B[7]);
        if (lq == 2) { avA = make_uint4(0x3f80u, 0u, 0u, 0u); avB = avA; }
        if (lq == 3) { avA = make_uint4(0u, 0u, 0u, 0u); avB = avA; }
      }
      bf16x8 aA = *(bf16x8*)&avA;
      bf16x8 aB = *(bf16x8*)&avB;
      #pragma unroll
      for (int nt = 0; nt < 4; nt++) {
        // per-lane B-frag: one aligned b128 from global (L2); 4 lq-lanes
        // share one 64 B line; independent across kt/nt -> deep MLP
        uint4 bv = *(const uint4*)(wgu + nt * (16 * KROW) + kt * 32);
        bf16x8 b = *(bf16x8*)&bv;
        accA[nt] = __builtin_amdgcn_mfma_f32_16x16x32_bf16(aA, b, accA[nt], 0, 0, 0);
        accB[nt] = __builtin_amdgcn_mfma_f32_16x16x32_bf16(aB, b, accB[nt], 0, 0, 0);
      }
    }

    // epilogue slab A: per-wave LDS transpose, lane (m=ln, o=lq) reduces w/ xvA
    #pragma unroll
    for (int nt = 0; nt < 4; nt++)
      #pragma unroll
      for (int r = 0; r < 4; r++)
        Dl[(w * 16 + lq * 4 + r) * DLP + nt * 16 + ln] = f2bf(accA[nt][r]);
    {
      const uint4* dp = (const uint4*)&Dl[(w * 16 + ln) * DLP + lq * 16];
      uint4 d0 = dp[0], d1 = dp[1];
      float r = 0.f;
      r = fmaf(bflo(d0.x), xvA[0],  r); r = fmaf(bfhi(d0.x), xvA[1],  r);
      r = fmaf(bflo(d0.y), xvA[2],  r); r = fmaf(bfhi(d0.y), xvA[3],  r);
      r = fmaf(bflo(d0.z), xvA[4],  r); r = fmaf(bfhi(d0.z), xvA[5],  r);
      r = fmaf(bflo(d0.w), xvA[6],  r); r = fmaf(bfhi(d0.w), xvA[7],  r);
      r = fmaf(bflo(d1.x), xvA[8],  r); r = fmaf(bfhi(d1.x), xvA[9],  r);
      r = fmaf(bflo(d1.y), xvA[10], r); r = fmaf(bfhi(d1.y), xvA[11], r);
      r = fmaf(bflo(d1.z), xvA[12], r); r = fmaf(bfhi(d1.z), xvA[13], r);
      r = fmaf(bflo(d1.w), xvA[14], r); r = fmaf(bfhi(d1.w), xvA[15], r);
      if (rowA < s1)
        y[((size_t)svA * CC + c) * 4 + lq] = r;
    }
    // epilogue slab B (Dl reused; same-wave LDS ordering)
    #pragma unroll
    for (int nt = 0; nt < 4; nt++)
      #pragma unroll
      for (int r = 0; r < 4; r++)
        Dl[(w * 16 + lq * 4 + r) * DLP + nt * 16 + ln] = f2bf(accB[nt][r]);
    {
      const uint4* dp = (const uint4*)&Dl[(w * 16 + ln) * DLP + lq * 16];
      uint4 d0 = dp[0], d1 = dp[1];
      float r = 0.f;
      r = fmaf(bflo(d0.x), xvB[0],  r); r = fmaf(bfhi(d0.x), xvB[1],  r);
      r = fmaf(bflo(d0.y), xvB[2],  r); r = fmaf(bfhi(d0.y), xvB[3],  r);
      r = fmaf(bflo(d0.z), xvB[4],  r); r = fmaf(bfhi(d0.z), xvB[5],  r);
      r = fmaf(bflo(d0.w), xvB[6],  r); r = fmaf(bfhi(d0.w), xvB[7],  r);
      r = fmaf(bflo(d1.x), xvB[8],  r); r = fmaf(bfhi(d1.x), xvB[9],  r);
      r = fmaf(bflo(d1.y), xvB[10], r); r = fmaf(bfhi(d1.y), xvB[11], r);
      r = fmaf(bflo(d1.z), xvB[12], r); r = fmaf(bfhi(d1.z), xvB[13], r);
      r = fmaf(bflo(d1.w), xvB[14], r); r = fmaf(bfhi(d1.w), xvB[15], r);
      if (rowB < s1)
        y[((size_t)svB * CC + c) * 4 + lq] = r;
    }

    // write prefetched x into wave-private xl (after all xv/epilogue reads)
    if (pf) {
      *(float4*)(&xl[0][w][ln][lq * 4]) = xc0;
      *(float4*)(&xl[1][w][ln][lq * 4]) = xc1;
    }
  }
}

// ============ lin_kernel: channel-mixing linear + pack ============
// grid 1024 (one node each) x 128 threads (n)
__global__ __launch_bounds__(128) void lin_kernel(
    const float* __restrict__ y, const float* __restrict__ w_lin,
    float* __restrict__ out) {
  int b = blockIdx.x;
  int n = threadIdx.x;
  const float4* yb4 = (const float4*)(y + (size_t)b * 512);
  float a0 = 0.f, a1 = 0.f, a2 = 0.f, a3 = 0.f;
  #pragma unroll 8
  for (int cc = 0; cc < CC; cc++) {
    float4 yv = yb4[cc];                        // uniform broadcast
    float wl0 = w_lin[(size_t)cc * CC + n];     // g=0
    float wl1 = w_lin[16384 + (size_t)cc * CC + n];
    a0 = fmaf(yv.x, wl0, a0);
    a1 = fmaf(yv.y, wl1, a1);
    a2 = fmaf(yv.z, wl1, a2);
    a3 = fmaf(yv.w, wl1, a3);
  }
  const float scale = 0.08838834764831845f;  // 1/sqrt(128)
  out[(size_t)b * 512 + n] = a0 * scale;
  out[(size_t)b * 512 + 128 + (size_t)n * 3 + 0] = a1 * scale;
  out[(size_t)b * 512 + 128 + (size_t)n * 3 + 1] = a2 * scale;
  out[(size_t)b * 512 + 128 + (size_t)n * 3 + 2] = a3 * scale;
}

extern "C" void kernel_launch(void* const* d_in, const int* in_sizes, int n_in,
                              void* d_out, int out_size, void* d_ws, size_t ws_size,
                              hipStream_t stream) {
  const float* node_feats = (const float*)d_in[0];
  const float* u3_0 = (const float*)d_in[1];
  const float* u3_1 = (const float*)d_in[2];
  const float* u2_0 = (const float*)d_in[3];
  const float* u2_1 = (const float*)d_in[4];
  const float* u1_0 = (const float*)d_in[5];
  const float* u1_1 = (const float*)d_in[6];
  const float* w3   = (const float*)d_in[7];
  const float* w2   = (const float*)d_in[8];
  const float* w1   = (const float*)d_in[9];
  const float* wlin = (const float*)d_in[10];
  const int* species = (const int*)d_in[11];
  float* out = (float*)d_out;

  char* ws = (char*)d_ws;
  ushort* W  = (ushort*)ws;                  // 512*18432*2 = 18,874,368 B
  float* yb  = (float*)(ws + 18874368);      //  2,097,152 B
  int* sorted = (int*)(ws + 20971520);       //      4,096 B
  int* seg    = (int*)(ws + 20975616);       //         32 B

  pre_kernel<<<1025, 256, 0, stream>>>(u3_0, u3_1, w3, u2_0, u2_1, u1_0, u1_1,
                                       w2, w1, species, W, sorted, seg);
  corr_kernel<<<1024, 256, 0, stream>>>(node_feats, W, sorted, seg, yb);
  lin_kernel<<<1024, 128, 0, stream>>>(yb, wlin, out);
}

// Round 12
// 158.166 us; speedup vs baseline: 1.4056x; 1.4056x over previous
//
#include <hip/hip_runtime.h>
#include <hip/hip_bf16.h>

#define SS 4
#define CC 128
#define KROW 288      // W k-stride per n-row
#define WELEM 18432   // 64 n-rows * 288 k per (s,c)
#define NK3 23
#define NK2 5
#define NK1 2

typedef unsigned int uint;
typedef unsigned short ushort;
typedef __attribute__((ext_vector_type(8))) short bf16x8;
typedef __attribute__((ext_vector_type(4))) float f32x4;

__device__ __forceinline__ ushort f2bf(float f) {
  uint u = __float_as_uint(f);
  return (ushort)((u + 0x7fffu + ((u >> 16) & 1u)) >> 16);
}
__device__ __forceinline__ uint pk2(float a, float b) {
  __hip_bfloat162 h = __float22bfloat162_rn(make_float2(a, b));  // v_cvt_pk_bf16_f32
  return *(uint*)&h;
}

// ============ pre_kernel: fold3 (blocks 0..511) + fold21 (512..1023) + sort (1024) ============
// W layout: [s][c][n=o*16+i][k 0..287] — k-contiguous so corr's per-lane A-frag
// (8 consecutive k) is one aligned b128 global load.
__global__ __launch_bounds__(256) void pre_kernel(
    const float* __restrict__ u3_0, const float* __restrict__ u3_1,
    const float* __restrict__ w3,
    const float* __restrict__ u2_0, const float* __restrict__ u2_1,
    const float* __restrict__ u1_0, const float* __restrict__ u1_1,
    const float* __restrict__ w2,  const float* __restrict__ w1,
    const int* __restrict__ sp, ushort* __restrict__ W,
    int* __restrict__ sorted, int* __restrict__ seg) {
  __shared__ float smem[5888 + NK3 * 64];
  int bx = blockIdx.x;
  int tid = threadIdx.x;

  if (bx < 512) {
    // ---- fold3: W main k=0..255 ----
    float* u3s = smem;            // 5888 floats
    float* w3s = smem + 5888;     // 23*64 floats
    int ch = bx & 1, i = (bx >> 1) & 15, o = (bx >> 5) & 3, s = bx >> 7;
    int g = (o > 0) ? 1 : 0, og = g ? (o - 1) : 0;
    const float* u3 = g ? u3_1 : u3_0;

    const float4* u3p = (const float4*)(u3 + (size_t)(og * 16 + i) * 5888);
    for (int d = tid; d < 1472; d += 256) {
      float4 v = u3p[d];
      u3s[4 * d] = v.x; u3s[4 * d + 1] = v.y; u3s[4 * d + 2] = v.z; u3s[4 * d + 3] = v.w;
    }
    for (int t = tid; t < NK3 * 64; t += 256) {
      int k = t >> 6, cp = t & 63;
      w3s[t] = w3[((size_t)(g * SS + s) * NK3 + k) * CC + ch * 64 + cp];
    }
    __syncthreads();

    float acc[64];
    #pragma unroll
    for (int q = 0; q < 64; q++) acc[q] = 0.f;
    int jl = tid;
    for (int k = 0; k < NK3; k++) {
      float u3v = u3s[jl * NK3 + k];
      const float4* wp = (const float4*)&w3s[k * 64];
      #pragma unroll
      for (int cq = 0; cq < 16; cq++) {
        float4 wv = wp[cq];
        acc[cq * 4 + 0] = fmaf(u3v, wv.x, acc[cq * 4 + 0]);
        acc[cq * 4 + 1] = fmaf(u3v, wv.y, acc[cq * 4 + 1]);
        acc[cq * 4 + 2] = fmaf(u3v, wv.z, acc[cq * 4 + 2]);
        acc[cq * 4 + 3] = fmaf(u3v, wv.w, acc[cq * 4 + 3]);
      }
    }
    int n = o * 16 + i;
    #pragma unroll
    for (int cp = 0; cp < 64; cp++) {
      W[(size_t)(s * CC + ch * 64 + cp) * WELEM + n * KROW + jl] = f2bf(acc[cp]);
    }
  } else if (bx < 1024) {
    // ---- fold21: W tail k=256..287 (one uint4 per thread) ----
    int b2 = bx - 512;
    int s = b2 >> 7, c = b2 & 127;
    int n = tid >> 2, lq = tid & 3;
    int o = n >> 4, i = n & 15;
    int g = (o > 0) ? 1 : 0, og = g ? (o - 1) : 0;
    const float* u2 = g ? u2_1 : u2_0;
    const float* u1 = g ? u1_1 : u1_0;

    float vals[8];
    #pragma unroll
    for (int t = 0; t < 8; t++) {
      int k = 256 + lq * 8 + t;
      float v = 0.f;
      if (k < 272) {
        int j = k - 256;
        #pragma unroll
        for (int k2 = 0; k2 < NK2; k2++)
          v = fmaf(u2[((size_t)(og * 16 + i) * 16 + j) * NK2 + k2],
                   w2[((size_t)(g * SS + s) * NK2 + k2) * CC + c], v);
      } else if (k == 272) {
        #pragma unroll
        for (int k2 = 0; k2 < NK1; k2++)
          v = fmaf(u1[(size_t)(og * 16 + i) * NK1 + k2],
                   w1[((size_t)(g * SS + s) * NK1 + k2) * CC + c], v);
      }
      vals[t] = v;
    }
    uint4 pk;
    pk.x = pk2(vals[0], vals[1]); pk.y = pk2(vals[2], vals[3]);
    pk.z = pk2(vals[4], vals[5]); pk.w = pk2(vals[6], vals[7]);
    *(uint4*)(W + (size_t)(s * CC + c) * WELEM + n * KROW + 256 + lq * 8) = pk;
  } else {
    // ---- sort nodes by species ----
    __shared__ int cnt[SS];
    __shared__ int basep[SS + 1];
    if (tid < SS) cnt[tid] = 0;
    __syncthreads();
    int mysp[4], mypos[4];
    #pragma unroll
    for (int q = 0; q < 4; q++) {
      int node = q * 256 + tid;
      int s = sp[node];
      mysp[q] = s;
      mypos[q] = atomicAdd(&cnt[s], 1);
    }
    __syncthreads();
    if (tid == 0) {
      basep[0] = 0;
      for (int q = 0; q < SS; q++) basep[q + 1] = basep[q] + cnt[q];
      for (int q = 0; q <= SS; q++) seg[q] = basep[q];
    }
    __syncthreads();
    #pragma unroll
    for (int q = 0; q < 4; q++)
      sorted[basep[mysp[q]] + mypos[q]] = q * 256 + tid;
  }
}

// ============ corr_kernel: transposed MFMA — A = W (registers), B = P (built) ============
// grid 1024 = h(2) x s(4) x c(128); 4 waves; wave w owns output o=w.
// A-frags (W rows n=w*16..w*16+15, M-dim) loaded ONCE into 36 VGPRs — W never
// touches LDS and is read exactly once per block. Per 16-node group: build B
// (P column of own node) from 16 x-regs, 9 MFMA, epilogue = 4 fma + 2 shfl.
// ZERO LDS, ZERO barriers, no large transients (spill lessons R5/R6/R7/R11).
__global__ __launch_bounds__(256, 2) void corr_kernel(
    const float* __restrict__ xg, const ushort* __restrict__ Wg,
    const int* __restrict__ sorted, const int* __restrict__ seg,
    float* __restrict__ y) {
  int bx = blockIdx.x;
  int h = bx >> 9, s = (bx >> 7) & 3, c = bx & 127;
  int tid = threadIdx.x;
  int w = tid >> 6, lane = tid & 63;
  int lq = lane >> 4, ln = lane & 15;

  // A-fragments: A[m=ln][k=lq*8+j] = W[n = w*16+ln][k = kt*32+lq*8+j]
  const ushort* wa = Wg + (size_t)(s * CC + c) * WELEM + (w * 16 + ln) * KROW + lq * 8;
  uint4 A0 = *(const uint4*)(wa);
  uint4 A1 = *(const uint4*)(wa + 32);
  uint4 A2 = *(const uint4*)(wa + 64);
  uint4 A3 = *(const uint4*)(wa + 96);
  uint4 A4 = *(const uint4*)(wa + 128);
  uint4 A5 = *(const uint4*)(wa + 160);
  uint4 A6 = *(const uint4*)(wa + 192);
  uint4 A7 = *(const uint4*)(wa + 224);
  uint4 A8 = *(const uint4*)(wa + 256);

  int s0 = seg[s], s1 = seg[s + 1];
  int ngroup = (s1 - s0 + 15) >> 4;
  int gh = (ngroup + 1) >> 1;
  int g0 = h * gh, g1 = min(ngroup, g0 + gh);

  for (int t = g0; t < g1; t++) {
    int row = s0 + t * 16 + ln;          // this lane's node (column ln of B)
    int sv = sorted[min(row, s1 - 1)];
    const float4* xp = (const float4*)(xg + ((size_t)sv * CC + c) * 16);
    float4 x0 = xp[0], x1 = xp[1], x2 = xp[2], x3 = xp[3];
    float xv[16];
    xv[0] = x0.x; xv[1] = x0.y; xv[2]  = x0.z; xv[3]  = x0.w;
    xv[4] = x1.x; xv[5] = x1.y; xv[6]  = x1.z; xv[7]  = x1.w;
    xv[8] = x2.x; xv[9] = x2.y; xv[10] = x2.z; xv[11] = x2.w;
    xv[12] = x3.x; xv[13] = x3.y; xv[14] = x3.z; xv[15] = x3.w;

    float xs8[8];
    #pragma unroll
    for (int q = 0; q < 8; q++) xs8[q] = (lq & 1) ? xv[8 + q] : xv[q];

    f32x4 acc = (f32x4){0.f, 0.f, 0.f, 0.f};

    #pragma unroll
    for (int kt = 0; kt < 9; kt++) {
      uint4 bv;
      if (kt < 8) {
        // B[k=lq*8+j][n=ln] = P[jl = kt*32+lq*8+j] = x_j0 * x_l0
        float xj = (lq & 2) ? xv[kt * 2 + 1] : xv[kt * 2];
        bv.x = pk2(xj * xs8[0], xj * xs8[1]);
        bv.y = pk2(xj * xs8[2], xj * xs8[3]);
        bv.z = pk2(xj * xs8[4], xj * xs8[5]);
        bv.w = pk2(xj * xs8[6], xj * xs8[7]);
      } else {
        bv.x = pk2(xs8[0], xs8[1]);
        bv.y = pk2(xs8[2], xs8[3]);
        bv.z = pk2(xs8[4], xs8[5]);
        bv.w = pk2(xs8[6], xs8[7]);
        if (lq == 2) bv = make_uint4(0x3f80u, 0u, 0u, 0u);  // constant-1 column (k=272)
        if (lq == 3) bv = make_uint4(0u, 0u, 0u, 0u);
      }
      bf16x8 b = *(bf16x8*)&bv;
      uint4 av;
      switch (kt) {
        case 0: av = A0; break; case 1: av = A1; break; case 2: av = A2; break;
        case 3: av = A3; break; case 4: av = A4; break; case 5: av = A5; break;
        case 6: av = A6; break; case 7: av = A7; break; default: av = A8; break;
      }
      bf16x8 a = *(bf16x8*)&av;
      acc = __builtin_amdgcn_mfma_f32_16x16x32_bf16(a, b, acc, 0, 0, 0);
    }

    // epilogue: D[row=i=lq*4+r][col=node=ln]; y[node][o=w] = sum_i D*x[node][i]
    float p = acc[0] * xv[lq * 4 + 0];
    p = fmaf(acc[1], xv[lq * 4 + 1], p);
    p = fmaf(acc[2], xv[lq * 4 + 2], p);
    p = fmaf(acc[3], xv[lq * 4 + 3], p);
    p += __shfl_xor(p, 16, 64);
    p += __shfl_xor(p, 32, 64);
    if (lq == 0 && row < s1)
      y[((size_t)sv * CC + c) * 4 + w] = p;
  }
}

// ============ lin_kernel: channel-mixing linear + pack ============
// grid 1024 (one node each) x 128 threads (n)
__global__ __launch_bounds__(128) void lin_kernel(
    const float* __restrict__ y, const float* __restrict__ w_lin,
    float* __restrict__ out) {
  int b = blockIdx.x;
  int n = threadIdx.x;
  const float4* yb4 = (const float4*)(y + (size_t)b * 512);
  float a0 = 0.f, a1 = 0.f, a2 = 0.f, a3 = 0.f;
  #pragma unroll 8
  for (int cc = 0; cc < CC; cc++) {
    float4 yv = yb4[cc];                        // uniform broadcast
    float wl0 = w_lin[(size_t)cc * CC + n];     // g=0
    float wl1 = w_lin[16384 + (size_t)cc * CC + n];
    a0 = fmaf(yv.x, wl0, a0);
    a1 = fmaf(yv.y, wl1, a1);
    a2 = fmaf(yv.z, wl1, a2);
    a3 = fmaf(yv.w, wl1, a3);
  }
  const float scale = 0.08838834764831845f;  // 1/sqrt(128)
  out[(size_t)b * 512 + n] = a0 * scale;
  out[(size_t)b * 512 + 128 + (size_t)n * 3 + 0] = a1 * scale;
  out[(size_t)b * 512 + 128 + (size_t)n * 3 + 1] = a2 * scale;
  out[(size_t)b * 512 + 128 + (size_t)n * 3 + 2] = a3 * scale;
}

extern "C" void kernel_launch(void* const* d_in, const int* in_sizes, int n_in,
                              void* d_out, int out_size, void* d_ws, size_t ws_size,
                              hipStream_t stream) {
  const float* node_feats = (const float*)d_in[0];
  const float* u3_0 = (const float*)d_in[1];
  const float* u3_1 = (const float*)d_in[2];
  const float* u2_0 = (const float*)d_in[3];
  const float* u2_1 = (const float*)d_in[4];
  const float* u1_0 = (const float*)d_in[5];
  const float* u1_1 = (const float*)d_in[6];
  const float* w3   = (const float*)d_in[7];
  const float* w2   = (const float*)d_in[8];
  const float* w1   = (const float*)d_in[9];
  const float* wlin = (const float*)d_in[10];
  const int* species = (const int*)d_in[11];
  float* out = (float*)d_out;

  char* ws = (char*)d_ws;
  ushort* W  = (ushort*)ws;                  // 512*18432*2 = 18,874,368 B
  float* yb  = (float*)(ws + 18874368);      //  2,097,152 B
  int* sorted = (int*)(ws + 20971520);       //      4,096 B
  int* seg    = (int*)(ws + 20975616);       //         32 B

  pre_kernel<<<1025, 256, 0, stream>>>(u3_0, u3_1, w3, u2_0, u2_1, u1_0, u1_1,
                                       w2, w1, species, W, sorted, seg);
  corr_kernel<<<1024, 256, 0, stream>>>(node_feats, W, sorted, seg, yb);
  lin_kernel<<<1024, 128, 0, stream>>>(yb, wlin, out);
}

// Round 13
// 142.939 us; speedup vs baseline: 1.5553x; 1.1065x over previous
//
#include <hip/hip_runtime.h>
#include <hip/hip_bf16.h>

#define SS 4
#define CC 128
#define KROW 288      // W k-stride per n-row
#define WELEM 18432   // 64 n-rows * 288 k per (s,c)
#define NK3 23
#define NK2 5
#define NK1 2

typedef unsigned int uint;
typedef unsigned short ushort;
typedef __attribute__((ext_vector_type(8))) short bf16x8;
typedef __attribute__((ext_vector_type(4))) float f32x4;

__device__ __forceinline__ ushort f2bf(float f) {
  uint u = __float_as_uint(f);
  return (ushort)((u + 0x7fffu + ((u >> 16) & 1u)) >> 16);
}
__device__ __forceinline__ uint pk2(float a, float b) {
  __hip_bfloat162 h = __float22bfloat162_rn(make_float2(a, b));  // v_cvt_pk_bf16_f32
  return *(uint*)&h;
}

// ============ pre_kernel: fold3 (blocks 0..511) + fold21 (512..1023) + sort (1024) ============
// W layout: [s][c][n=o*16+i][k 0..287] — k-contiguous so corr's per-lane A-frag
// (8 consecutive k) is one aligned b128 global load.
__global__ __launch_bounds__(256) void pre_kernel(
    const float* __restrict__ u3_0, const float* __restrict__ u3_1,
    const float* __restrict__ w3,
    const float* __restrict__ u2_0, const float* __restrict__ u2_1,
    const float* __restrict__ u1_0, const float* __restrict__ u1_1,
    const float* __restrict__ w2,  const float* __restrict__ w1,
    const int* __restrict__ sp, ushort* __restrict__ W,
    int* __restrict__ sorted, int* __restrict__ seg) {
  __shared__ float smem[5888 + NK3 * 64];
  int bx = blockIdx.x;
  int tid = threadIdx.x;

  if (bx < 512) {
    // ---- fold3: W main k=0..255 ----
    float* u3s = smem;            // 5888 floats
    float* w3s = smem + 5888;     // 23*64 floats
    int ch = bx & 1, i = (bx >> 1) & 15, o = (bx >> 5) & 3, s = bx >> 7;
    int g = (o > 0) ? 1 : 0, og = g ? (o - 1) : 0;
    const float* u3 = g ? u3_1 : u3_0;

    const float4* u3p = (const float4*)(u3 + (size_t)(og * 16 + i) * 5888);
    for (int d = tid; d < 1472; d += 256) {
      float4 v = u3p[d];
      u3s[4 * d] = v.x; u3s[4 * d + 1] = v.y; u3s[4 * d + 2] = v.z; u3s[4 * d + 3] = v.w;
    }
    for (int t = tid; t < NK3 * 64; t += 256) {
      int k = t >> 6, cp = t & 63;
      w3s[t] = w3[((size_t)(g * SS + s) * NK3 + k) * CC + ch * 64 + cp];
    }
    __syncthreads();

    float acc[64];
    #pragma unroll
    for (int q = 0; q < 64; q++) acc[q] = 0.f;
    int jl = tid;
    for (int k = 0; k < NK3; k++) {
      float u3v = u3s[jl * NK3 + k];
      const float4* wp = (const float4*)&w3s[k * 64];
      #pragma unroll
      for (int cq = 0; cq < 16; cq++) {
        float4 wv = wp[cq];
        acc[cq * 4 + 0] = fmaf(u3v, wv.x, acc[cq * 4 + 0]);
        acc[cq * 4 + 1] = fmaf(u3v, wv.y, acc[cq * 4 + 1]);
        acc[cq * 4 + 2] = fmaf(u3v, wv.z, acc[cq * 4 + 2]);
        acc[cq * 4 + 3] = fmaf(u3v, wv.w, acc[cq * 4 + 3]);
      }
    }
    int n = o * 16 + i;
    #pragma unroll
    for (int cp = 0; cp < 64; cp++) {
      W[(size_t)(s * CC + ch * 64 + cp) * WELEM + n * KROW + jl] = f2bf(acc[cp]);
    }
  } else if (bx < 1024) {
    // ---- fold21: W tail k=256..287 (one uint4 per thread) ----
    int b2 = bx - 512;
    int s = b2 >> 7, c = b2 & 127;
    int n = tid >> 2, lq = tid & 3;
    int o = n >> 4, i = n & 15;
    int g = (o > 0) ? 1 : 0, og = g ? (o - 1) : 0;
    const float* u2 = g ? u2_1 : u2_0;
    const float* u1 = g ? u1_1 : u1_0;

    float vals[8];
    #pragma unroll
    for (int t = 0; t < 8; t++) {
      int k = 256 + lq * 8 + t;
      float v = 0.f;
      if (k < 272) {
        int j = k - 256;
        #pragma unroll
        for (int k2 = 0; k2 < NK2; k2++)
          v = fmaf(u2[((size_t)(og * 16 + i) * 16 + j) * NK2 + k2],
                   w2[((size_t)(g * SS + s) * NK2 + k2) * CC + c], v);
      } else if (k == 272) {
        #pragma unroll
        for (int k2 = 0; k2 < NK1; k2++)
          v = fmaf(u1[(size_t)(og * 16 + i) * NK1 + k2],
                   w1[((size_t)(g * SS + s) * NK1 + k2) * CC + c], v);
      }
      vals[t] = v;
    }
    uint4 pk;
    pk.x = pk2(vals[0], vals[1]); pk.y = pk2(vals[2], vals[3]);
    pk.z = pk2(vals[4], vals[5]); pk.w = pk2(vals[6], vals[7]);
    *(uint4*)(W + (size_t)(s * CC + c) * WELEM + n * KROW + 256 + lq * 8) = pk;
  } else {
    // ---- sort nodes by species ----
    __shared__ int cnt[SS];
    __shared__ int basep[SS + 1];
    if (tid < SS) cnt[tid] = 0;
    __syncthreads();
    int mysp[4], mypos[4];
    #pragma unroll
    for (int q = 0; q < 4; q++) {
      int node = q * 256 + tid;
      int s = sp[node];
      mysp[q] = s;
      mypos[q] = atomicAdd(&cnt[s], 1);
    }
    __syncthreads();
    if (tid == 0) {
      basep[0] = 0;
      for (int q = 0; q < SS; q++) basep[q + 1] = basep[q] + cnt[q];
      for (int q = 0; q <= SS; q++) seg[q] = basep[q];
    }
    __syncthreads();
    #pragma unroll
    for (int q = 0; q < 4; q++)
      sorted[basep[mysp[q]] + mypos[q]] = q * 256 + tid;
  }
}

// ============ corr_kernel: transposed MFMA — A = W (registers), B = P (built) ============
// grid 1024 = h(2) x s(4) x c(128); 4 waves; wave w owns output o=w.
// A-frags (W rows n=w*16..w*16+15) loaded ONCE into 36 VGPRs — no LDS staging,
// W read exactly once. Per 16-node group: build B from x-regs, 9 MFMA,
// epilogue = 12 cndmask + 4 fma + 2 shfl. ZERO __shared__, ZERO barriers.
// R12 lesson: the epilogue's xv[lq*4+r] RUNTIME index made AMDGPUPromoteAlloca
// demote xv to LDS (LDS_Block_Size=16K, 11.76M bank conflicts, 62 us) —
// all xv indices must be unroll-constant; runtime selection via cndmask chains.
__global__ __launch_bounds__(256, 2) void corr_kernel(
    const float* __restrict__ xg, const ushort* __restrict__ Wg,
    const int* __restrict__ sorted, const int* __restrict__ seg,
    float* __restrict__ y) {
  int bx = blockIdx.x;
  int h = bx >> 9, s = (bx >> 7) & 3, c = bx & 127;
  int tid = threadIdx.x;
  int w = tid >> 6, lane = tid & 63;
  int lq = lane >> 4, ln = lane & 15;

  // A-fragments: A[m=ln][k=lq*8+j] = W[n = w*16+ln][k = kt*32+lq*8+j]
  const ushort* wa = Wg + (size_t)(s * CC + c) * WELEM + (w * 16 + ln) * KROW + lq * 8;
  uint4 A0 = *(const uint4*)(wa);
  uint4 A1 = *(const uint4*)(wa + 32);
  uint4 A2 = *(const uint4*)(wa + 64);
  uint4 A3 = *(const uint4*)(wa + 96);
  uint4 A4 = *(const uint4*)(wa + 128);
  uint4 A5 = *(const uint4*)(wa + 160);
  uint4 A6 = *(const uint4*)(wa + 192);
  uint4 A7 = *(const uint4*)(wa + 224);
  uint4 A8 = *(const uint4*)(wa + 256);

  int s0 = seg[s], s1 = seg[s + 1];
  int ngroup = (s1 - s0 + 15) >> 4;
  int gh = (ngroup + 1) >> 1;
  int g0 = h * gh, g1 = min(ngroup, g0 + gh);

  for (int t = g0; t < g1; t++) {
    int row = s0 + t * 16 + ln;          // this lane's node (column ln of B)
    int sv = sorted[min(row, s1 - 1)];
    const float4* xp = (const float4*)(xg + ((size_t)sv * CC + c) * 16);
    float4 x0 = xp[0], x1 = xp[1], x2 = xp[2], x3 = xp[3];
    float xv[16];
    xv[0] = x0.x; xv[1] = x0.y; xv[2]  = x0.z; xv[3]  = x0.w;
    xv[4] = x1.x; xv[5] = x1.y; xv[6]  = x1.z; xv[7]  = x1.w;
    xv[8] = x2.x; xv[9] = x2.y; xv[10] = x2.z; xv[11] = x2.w;
    xv[12] = x3.x; xv[13] = x3.y; xv[14] = x3.z; xv[15] = x3.w;

    float xs8[8];
    #pragma unroll
    for (int q = 0; q < 8; q++) xs8[q] = (lq & 1) ? xv[8 + q] : xv[q];

    f32x4 acc = (f32x4){0.f, 0.f, 0.f, 0.f};

    #pragma unroll
    for (int kt = 0; kt < 9; kt++) {
      uint4 bv;
      if (kt < 8) {
        // B[k=lq*8+j][n=ln] = P[jl = kt*32+lq*8+j] = x_j0 * x_l0
        float xj = (lq & 2) ? xv[kt * 2 + 1] : xv[kt * 2];
        bv.x = pk2(xj * xs8[0], xj * xs8[1]);
        bv.y = pk2(xj * xs8[2], xj * xs8[3]);
        bv.z = pk2(xj * xs8[4], xj * xs8[5]);
        bv.w = pk2(xj * xs8[6], xj * xs8[7]);
      } else {
        bv.x = pk2(xs8[0], xs8[1]);
        bv.y = pk2(xs8[2], xs8[3]);
        bv.z = pk2(xs8[4], xs8[5]);
        bv.w = pk2(xs8[6], xs8[7]);
        if (lq == 2) bv = make_uint4(0x3f80u, 0u, 0u, 0u);  // constant-1 column (k=272)
        if (lq == 3) bv = make_uint4(0u, 0u, 0u, 0u);
      }
      bf16x8 b = *(bf16x8*)&bv;
      uint4 av;
      switch (kt) {
        case 0: av = A0; break; case 1: av = A1; break; case 2: av = A2; break;
        case 3: av = A3; break; case 4: av = A4; break; case 5: av = A5; break;
        case 6: av = A6; break; case 7: av = A7; break; default: av = A8; break;
      }
      bf16x8 a = *(bf16x8*)&av;
      acc = __builtin_amdgcn_mfma_f32_16x16x32_bf16(a, b, acc, 0, 0, 0);
    }

    // epilogue: D[row=i=lq*4+r][col=node=ln]; y[node][o=w] = sum_i D*x[node][i]
    // lq is RUNTIME -> select with constant-indexed ternaries (no dynamic array idx)
    float e0 = (lq == 0) ? xv[0] : (lq == 1) ? xv[4] : (lq == 2) ? xv[8]  : xv[12];
    float e1 = (lq == 0) ? xv[1] : (lq == 1) ? xv[5] : (lq == 2) ? xv[9]  : xv[13];
    float e2 = (lq == 0) ? xv[2] : (lq == 1) ? xv[6] : (lq == 2) ? xv[10] : xv[14];
    float e3 = (lq == 0) ? xv[3] : (lq == 1) ? xv[7] : (lq == 2) ? xv[11] : xv[15];
    float p = acc[0] * e0;
    p = fmaf(acc[1], e1, p);
    p = fmaf(acc[2], e2, p);
    p = fmaf(acc[3], e3, p);
    p += __shfl_xor(p, 16, 64);
    p += __shfl_xor(p, 32, 64);
    if (lq == 0 && row < s1)
      y[((size_t)sv * CC + c) * 4 + w] = p;
  }
}

// ============ lin_kernel: channel-mixing linear + pack ============
// grid 1024 (one node each) x 128 threads (n)
__global__ __launch_bounds__(128) void lin_kernel(
    const float* __restrict__ y, const float* __restrict__ w_lin,
    float* __restrict__ out) {
  int b = blockIdx.x;
  int n = threadIdx.x;
  const float4* yb4 = (const float4*)(y + (size_t)b * 512);
  float a0 = 0.f, a1 = 0.f, a2 = 0.f, a3 = 0.f;
  #pragma unroll 8
  for (int cc = 0; cc < CC; cc++) {
    float4 yv = yb4[cc];                        // uniform broadcast
    float wl0 = w_lin[(size_t)cc * CC + n];     // g=0
    float wl1 = w_lin[16384 + (size_t)cc * CC + n];
    a0 = fmaf(yv.x, wl0, a0);
    a1 = fmaf(yv.y, wl1, a1);
    a2 = fmaf(yv.z, wl1, a2);
    a3 = fmaf(yv.w, wl1, a3);
  }
  const float scale = 0.08838834764831845f;  // 1/sqrt(128)
  out[(size_t)b * 512 + n] = a0 * scale;
  out[(size_t)b * 512 + 128 + (size_t)n * 3 + 0] = a1 * scale;
  out[(size_t)b * 512 + 128 + (size_t)n * 3 + 1] = a2 * scale;
  out[(size_t)b * 512 + 128 + (size_t)n * 3 + 2] = a3 * scale;
}

extern "C" void kernel_launch(void* const* d_in, const int* in_sizes, int n_in,
                              void* d_out, int out_size, void* d_ws, size_t ws_size,
                              hipStream_t stream) {
  const float* node_feats = (const float*)d_in[0];
  const float* u3_0 = (const float*)d_in[1];
  const float* u3_1 = (const float*)d_in[2];
  const float* u2_0 = (const float*)d_in[3];
  const float* u2_1 = (const float*)d_in[4];
  const float* u1_0 = (const float*)d_in[5];
  const float* u1_1 = (const float*)d_in[6];
  const float* w3   = (const float*)d_in[7];
  const float* w2   = (const float*)d_in[8];
  const float* w1   = (const float*)d_in[9];
  const float* wlin = (const float*)d_in[10];
  const int* species = (const int*)d_in[11];
  float* out = (float*)d_out;

  char* ws = (char*)d_ws;
  ushort* W  = (ushort*)ws;                  // 512*18432*2 = 18,874,368 B
  float* yb  = (float*)(ws + 18874368);      //  2,097,152 B
  int* sorted = (int*)(ws + 20971520);       //      4,096 B
  int* seg    = (int*)(ws + 20975616);       //         32 B

  pre_kernel<<<1025, 256, 0, stream>>>(u3_0, u3_1, w3, u2_0, u2_1, u1_0, u1_1,
                                       w2, w1, species, W, sorted, seg);
  corr_kernel<<<1024, 256, 0, stream>>>(node_feats, W, sorted, seg, yb);
  lin_kernel<<<1024, 128, 0, stream>>>(yb, wlin, out);
}